// Round 1
// baseline (935.436 us; speedup 1.0000x reference)
//
#include <hip/hip_runtime.h>
#include <math.h>

// Problem constants (B,L,D fixed by the reference)
#define NB 4
#define LL 2048
#define DD 256
#define TT 64
#define NT (LL/TT)          // 32 tiles along L
#define LDSP (DD+4)         // padded LDS row (float4-aligned, kills bank conflicts)
#define EPS 1e-7f

typedef float f4 __attribute__((ext_vector_type(4)));

// Cooperative 64x256 tile load, fully coalesced (each wave reads whole 1KB rows)
__device__ inline void load_tile(const float* __restrict__ g, float (*lds)[LDSP], int tid) {
#pragma unroll
    for (int m = 0; m < 16; ++m) {
        int row = m * 4 + (tid >> 6);
        int c4  = tid & 63;
        f4 v = *(const f4*)(g + (size_t)row * DD + c4 * 4);
        *(f4*)(&lds[row][c4 * 4]) = v;
    }
}

// rowterm[t] = 2*sum_{s<t}(k_t.k_s)^2 + (k_t.k_t)^2   (per batch)
__global__ __launch_bounds__(256) void k_gram(const float* __restrict__ kin,
                                              float* __restrict__ rowterm) {
    int bid = blockIdx.x;
    int b = bid / NT, it = bid % NT;
    const float* kb = kin + (size_t)b * LL * DD;
    __shared__ float Kt[TT][LDSP];
    __shared__ float Ks[TT][LDSP];
    int tid = threadIdx.x;
    load_tile(kb + (size_t)it * TT * DD, Kt, tid);
    int rg = tid >> 4;   // 0..15  rows r = rg + 16*i
    int sg = tid & 15;   // 0..15  cols s2 = sg + 16*j (interleaved -> 2-way LDS max)
    int itbase = it * TT;
    float acc[4] = {0.f, 0.f, 0.f, 0.f};
    for (int js = 0; js <= it; ++js) {
        __syncthreads();
        load_tile(kb + (size_t)js * TT * DD, Ks, tid);
        __syncthreads();
        float dv[4][4];
#pragma unroll
        for (int i = 0; i < 4; ++i)
#pragma unroll
            for (int j = 0; j < 4; ++j) dv[i][j] = 0.f;
        for (int d4 = 0; d4 < DD / 4; ++d4) {
            f4 a[4], bb[4];
#pragma unroll
            for (int i = 0; i < 4; ++i) a[i]  = *(const f4*)&Kt[rg + 16 * i][d4 * 4];
#pragma unroll
            for (int j = 0; j < 4; ++j) bb[j] = *(const f4*)&Ks[sg + 16 * j][d4 * 4];
#pragma unroll
            for (int i = 0; i < 4; ++i)
#pragma unroll
                for (int j = 0; j < 4; ++j) {
                    float t = dv[i][j];
                    t = fmaf(a[i][0], bb[j][0], t);
                    t = fmaf(a[i][1], bb[j][1], t);
                    t = fmaf(a[i][2], bb[j][2], t);
                    t = fmaf(a[i][3], bb[j][3], t);
                    dv[i][j] = t;
                }
        }
        int sbase = js * TT;
#pragma unroll
        for (int i = 0; i < 4; ++i) {
            int tg = itbase + rg + 16 * i;
#pragma unroll
            for (int j = 0; j < 4; ++j) {
                int s = sbase + sg + 16 * j;
                float w = (s < tg) ? 2.f : ((s == tg) ? 1.f : 0.f);
                acc[i] = fmaf(w * dv[i][j], dv[i][j], acc[i]);
            }
        }
    }
#pragma unroll
    for (int i = 0; i < 4; ++i) {
        float v = acc[i];
        v += __shfl_xor(v, 1);
        v += __shfl_xor(v, 2);
        v += __shfl_xor(v, 4);
        v += __shfl_xor(v, 8);
        if (sg == 0) rowterm[b * LL + itbase + rg + 16 * i] = v;
    }
}

// inv[t] = 1/(sqrt(prefix_sum(rowterm)[t]) + EPS)   (one block per batch)
__global__ __launch_bounds__(256) void k_scan(const float* __restrict__ rowterm,
                                              float* __restrict__ inv) {
    int b = blockIdx.x, tid = threadIdx.x;
    __shared__ float sd[256];
    const float* rt = rowterm + b * LL;
    float v[8];
    float s = 0.f;
#pragma unroll
    for (int m = 0; m < 8; ++m) { v[m] = rt[tid * 8 + m]; s += v[m]; }
    sd[tid] = s;
    __syncthreads();
    for (int off = 1; off < 256; off <<= 1) {
        float add = (tid >= off) ? sd[tid - off] : 0.f;
        __syncthreads();
        sd[tid] += add;
        __syncthreads();
    }
    float run = sd[tid] - s;   // exclusive prefix of this thread's chunk
#pragma unroll
    for (int m = 0; m < 8; ++m) {
        run += v[m];
        inv[b * LL + tid * 8 + m] = 1.f / (sqrtf(run) + EPS);
    }
}

// O[t] = sum_{s<=t} (q_t.k_s) k_s ; out = tanh(gain * O*inv) * scale
__global__ __launch_bounds__(256) void k_main(const float* __restrict__ qin,
                                              const float* __restrict__ kin,
                                              const float* __restrict__ inv,
                                              const float* __restrict__ gain,
                                              const float* __restrict__ oscale,
                                              float* __restrict__ qout) {
    int bid = blockIdx.x;
    int b = bid / NT, it = bid % NT;
    const float* qb = qin + (size_t)b * LL * DD;
    const float* kb = kin + (size_t)b * LL * DD;
    __shared__ float Qt[TT][LDSP];
    __shared__ float Ks[TT][LDSP];
    __shared__ float At[TT][68];   // stored TRANSPOSED: At[s][r]
    int tid = threadIdx.x;
    load_tile(qb + (size_t)it * TT * DD, Qt, tid);
    int rg = tid >> 4;   // A-compute rows r = rg + 16*i
    int sg = tid & 15;   // A-compute cols s2 = sg + 16*j
    int rgO = tid >> 4;  // O rows: 4*rgO + i (contiguous 4 -> f4 read of At)
    int cgO = tid & 15;  // O f4-cols: cgO + 16*m
    int itbase = it * TT;
    f4 o[4][4];
#pragma unroll
    for (int i = 0; i < 4; ++i)
#pragma unroll
        for (int m = 0; m < 4; ++m) o[i][m] = (f4){0.f, 0.f, 0.f, 0.f};

    for (int js = 0; js <= it; ++js) {
        __syncthreads();
        load_tile(kb + (size_t)js * TT * DD, Ks, tid);
        __syncthreads();
        // ---- A tile: dv[i][j] = q_{r}.k_{s2}
        float dv[4][4];
#pragma unroll
        for (int i = 0; i < 4; ++i)
#pragma unroll
            for (int j = 0; j < 4; ++j) dv[i][j] = 0.f;
        for (int d4 = 0; d4 < DD / 4; ++d4) {
            f4 a[4], bb[4];
#pragma unroll
            for (int i = 0; i < 4; ++i) a[i]  = *(const f4*)&Qt[rg + 16 * i][d4 * 4];
#pragma unroll
            for (int j = 0; j < 4; ++j) bb[j] = *(const f4*)&Ks[sg + 16 * j][d4 * 4];
#pragma unroll
            for (int i = 0; i < 4; ++i)
#pragma unroll
                for (int j = 0; j < 4; ++j) {
                    float t = dv[i][j];
                    t = fmaf(a[i][0], bb[j][0], t);
                    t = fmaf(a[i][1], bb[j][1], t);
                    t = fmaf(a[i][2], bb[j][2], t);
                    t = fmaf(a[i][3], bb[j][3], t);
                    dv[i][j] = t;
                }
        }
        int sbase = js * TT;
#pragma unroll
        for (int i = 0; i < 4; ++i) {
            int tg = itbase + rg + 16 * i;
#pragma unroll
            for (int j = 0; j < 4; ++j) {
                int s = sbase + sg + 16 * j;
                At[sg + 16 * j][rg + 16 * i] = (s <= tg) ? dv[i][j] : 0.f;
            }
        }
        __syncthreads();
        // ---- O += A * Ks  (each thread: rows 4*rgO..+3, f4-cols cgO+16m)
        for (int s = 0; s < TT; ++s) {
            f4 a4 = *(const f4*)&At[s][rgO * 4];
#pragma unroll
            for (int m = 0; m < 4; ++m) {
                f4 kv = *(const f4*)&Ks[s][(cgO + 16 * m) * 4];
#pragma unroll
                for (int i = 0; i < 4; ++i) {
                    o[i][m][0] = fmaf(a4[i], kv[0], o[i][m][0]);
                    o[i][m][1] = fmaf(a4[i], kv[1], o[i][m][1]);
                    o[i][m][2] = fmaf(a4[i], kv[2], o[i][m][2]);
                    o[i][m][3] = fmaf(a4[i], kv[3], o[i][m][3]);
                }
            }
        }
    }
    // ---- epilogue: tanh(gain * O*inv) * scale
#pragma unroll
    for (int i = 0; i < 4; ++i) {
        int t = itbase + rgO * 4 + i;
        float iv = inv[b * LL + t];
        float* outp = qout + ((size_t)b * LL + t) * DD;
#pragma unroll
        for (int m = 0; m < 4; ++m) {
            int c4 = cgO + 16 * m;
            f4 g4 = *(const f4*)(gain + c4 * 4);
            f4 s4 = *(const f4*)(oscale + c4 * 4);
            f4 r;
#pragma unroll
            for (int e = 0; e < 4; ++e)
                r[e] = tanhf(g4[e] * (o[i][m][e] * iv)) * s4[e];
            *(f4*)(outp + c4 * 4) = r;
        }
    }
}

// P_final = P_prev + K^T K  (64x64 output tiles, K-chunks staged transposed)
__global__ __launch_bounds__(256) void k_pfinal(const float* __restrict__ kin,
                                                const float* __restrict__ pprev,
                                                float* __restrict__ pout) {
    int bid = blockIdx.x;
    int b = bid >> 4, tix = (bid & 15) >> 2, tjx = bid & 3;
    __shared__ float KaT[64][68];   // [col i][l]
    __shared__ float KbT[64][68];   // [col j][l]
    int tid = threadIdx.x;
    const float* kb = kin + (size_t)b * LL * DD;
    int rgrp = tid >> 4, cgrp = tid & 15;
    float acc[4][4];
#pragma unroll
    for (int i = 0; i < 4; ++i)
#pragma unroll
        for (int j = 0; j < 4; ++j) acc[i][j] = 0.f;
    for (int ch = 0; ch < LL / 64; ++ch) {
        __syncthreads();
#pragma unroll
        for (int m = 0; m < 4; ++m) {
            int idx = m * 256 + tid;
            int l  = idx >> 4;
            int c4 = idx & 15;
            const float* ga = kb + (size_t)(ch * 64 + l) * DD + tix * 64 + c4 * 4;
            const float* gb = kb + (size_t)(ch * 64 + l) * DD + tjx * 64 + c4 * 4;
            f4 va = *(const f4*)ga;
            f4 vb = *(const f4*)gb;
#pragma unroll
            for (int e = 0; e < 4; ++e) {
                KaT[c4 * 4 + e][l] = va[e];
                KbT[c4 * 4 + e][l] = vb[e];
            }
        }
        __syncthreads();
        for (int l4 = 0; l4 < 16; ++l4) {
            f4 a[4], bb[4];
#pragma unroll
            for (int i = 0; i < 4; ++i) a[i]  = *(const f4*)&KaT[rgrp + 16 * i][l4 * 4];
#pragma unroll
            for (int j = 0; j < 4; ++j) bb[j] = *(const f4*)&KbT[cgrp + 16 * j][l4 * 4];
#pragma unroll
            for (int i = 0; i < 4; ++i)
#pragma unroll
                for (int j = 0; j < 4; ++j) {
                    float t = acc[i][j];
                    t = fmaf(a[i][0], bb[j][0], t);
                    t = fmaf(a[i][1], bb[j][1], t);
                    t = fmaf(a[i][2], bb[j][2], t);
                    t = fmaf(a[i][3], bb[j][3], t);
                    acc[i][j] = t;
                }
        }
    }
#pragma unroll
    for (int i = 0; i < 4; ++i)
#pragma unroll
        for (int j = 0; j < 4; ++j) {
            int ig = tix * 64 + rgrp + 16 * i;
            int jg = tjx * 64 + cgrp + 16 * j;
            size_t off = (size_t)b * DD * DD + (size_t)ig * DD + jg;
            pout[off] = acc[i][j] + pprev[off];
        }
}

extern "C" void kernel_launch(void* const* d_in, const int* in_sizes, int n_in,
                              void* d_out, int out_size, void* d_ws, size_t ws_size,
                              hipStream_t stream) {
    const float* q      = (const float*)d_in[0];
    const float* k      = (const float*)d_in[1];
    const float* pprev  = (const float*)d_in[2];
    const float* gain   = (const float*)d_in[3];
    const float* oscale = (const float*)d_in[4];
    float* qout = (float*)d_out;
    float* pout = (float*)d_out + (size_t)NB * LL * DD;
    // Use the P_final output region as scratch for rowterm/inv (16K floats);
    // k_pfinal overwrites it last. Zero dependence on ws_size.
    float* rowterm = pout;
    float* inv     = pout + NB * LL;

    k_gram  <<<NB * NT, 256, 0, stream>>>(k, rowterm);
    k_scan  <<<NB,      256, 0, stream>>>(rowterm, inv);
    k_main  <<<NB * NT, 256, 0, stream>>>(q, k, inv, gain, oscale, qout);
    k_pfinal<<<NB * 16, 256, 0, stream>>>(k, pprev, pout);
}

// Round 2
// 123.594 us; speedup vs baseline: 7.5686x; 7.5686x over previous
//
#include <hip/hip_runtime.h>
#include <math.h>

#define NB 4
#define LL 2048
#define DD 256
#define EPS 1e-7f

typedef float f4 __attribute__((ext_vector_type(4)));
typedef __attribute__((ext_vector_type(8))) short bhalf8;   // 8 bf16 in 4 VGPRs
typedef __attribute__((ext_vector_type(4))) float f32x4;

#define KROW_S 264   // row-major 64x256 bf16 tile, padded stride (elems)
#define KST_S  72    // transposed 256x64 bf16 tile, padded stride
#define AT_S   72    // masked-A 64x64 bf16 tile stride

// ---- helpers ----------------------------------------------------------------
__device__ __forceinline__ unsigned pack2(float lo, float hi) {
    // two f32 -> two bf16 (round-half-up) packed in one dword
    unsigned ulo = __float_as_uint(lo) + 0x8000u;
    unsigned uhi = __float_as_uint(hi) + 0x8000u;
    return __builtin_amdgcn_perm(uhi, ulo, 0x07060302u);
}
__device__ __forceinline__ unsigned short bf16of(float x) {
    return (unsigned short)((__float_as_uint(x) + 0x8000u) >> 16);
}
// transposed-K LDS offset with XOR bank swizzle (consistent for read & write)
__device__ __forceinline__ int kst_off(int d, int s) {
    return d * KST_S + (s ^ (((d >> 3) & 7) << 3));
}
__device__ __forceinline__ f32x4 mfma16(bhalf8 a, bhalf8 b, f32x4 c) {
    return __builtin_amdgcn_mfma_f32_16x16x32_bf16(a, b, c, 0, 0, 0);
}
// decode flattened causal-chunk id e in [0,80): row-tile it, chunk c (8 js-tiles each)
__device__ __forceinline__ void decode_chunk(int e, int& it, int& c) {
    int i = 0, acc = 0;
    while (true) { int n = (i >> 3) + 1; if (acc + n > e) break; acc += n; ++i; }
    it = i; c = e - acc;
}
// stage a 64x256 f32 tile -> row-major bf16 LDS (coalesced, b64 writes)
__device__ __forceinline__ void stage_row(const float* __restrict__ g,
                                          unsigned short* krow, int tid) {
#pragma unroll
    for (int m = 0; m < 16; ++m) {
        int row = m * 4 + (tid >> 6);
        int c4 = tid & 63;
        f4 v = *(const f4*)(g + (size_t)row * DD + c4 * 4);
        uint2 pv; pv.x = pack2(v[0], v[1]); pv.y = pack2(v[2], v[3]);
        *(uint2*)&krow[row * KROW_S + c4 * 4] = pv;
    }
}
// stage a 64x256 f32 tile -> BOTH row-major and transposed bf16 LDS
__device__ __forceinline__ void stage_dual(const float* __restrict__ g,
                                           unsigned short* krow,
                                           unsigned short* kst, int tid) {
#pragma unroll
    for (int iter = 0; iter < 4; ++iter) {
        int dq = (tid & 15) + 16 * iter;
        int sq = tid >> 4;
        const float* gs = g + (size_t)(4 * sq) * DD + 4 * dq;
        f4 v0 = *(const f4*)(gs);
        f4 v1 = *(const f4*)(gs + DD);
        f4 v2 = *(const f4*)(gs + 2 * DD);
        f4 v3 = *(const f4*)(gs + 3 * DD);
        {
            uint2 p0; p0.x = pack2(v0[0], v0[1]); p0.y = pack2(v0[2], v0[3]);
            *(uint2*)&krow[(4 * sq + 0) * KROW_S + 4 * dq] = p0;
            uint2 p1; p1.x = pack2(v1[0], v1[1]); p1.y = pack2(v1[2], v1[3]);
            *(uint2*)&krow[(4 * sq + 1) * KROW_S + 4 * dq] = p1;
            uint2 p2; p2.x = pack2(v2[0], v2[1]); p2.y = pack2(v2[2], v2[3]);
            *(uint2*)&krow[(4 * sq + 2) * KROW_S + 4 * dq] = p2;
            uint2 p3; p3.x = pack2(v3[0], v3[1]); p3.y = pack2(v3[2], v3[3]);
            *(uint2*)&krow[(4 * sq + 3) * KROW_S + 4 * dq] = p3;
        }
#pragma unroll
        for (int i = 0; i < 4; ++i) {
            uint2 pv; pv.x = pack2(v0[i], v1[i]); pv.y = pack2(v2[i], v3[i]);
            *(uint2*)&kst[kst_off(4 * dq + i, 4 * sq)] = pv;
        }
    }
}

// ---- gram: rowterm[t] = 2*sum_{s<t}(k_t.k_s)^2 + (k_t.k_t)^2 (atomic accum) --
__global__ __launch_bounds__(256, 2) void k_gram(const float* __restrict__ kin,
                                                 float* __restrict__ rowterm) {
    __shared__ __align__(16) unsigned short sKrow[64 * KROW_S];
    int bid = blockIdx.x;
    int b = bid / 80;
    int it, c; decode_chunk(bid % 80, it, c);
    int js0 = c * 8, js1 = (js0 + 8 < it + 1) ? js0 + 8 : it + 1;
    const float* kb = kin + (size_t)b * LL * DD;
    int tid = threadIdx.x, lane = tid & 63, w = tid >> 6;
    int wr = w >> 1, wc = w & 1, ln = lane & 15, g = lane >> 4;

    stage_row(kb + (size_t)it * 64 * DD, sKrow, tid);
    __syncthreads();
    bhalf8 ktf[2][8];
#pragma unroll
    for (int rt = 0; rt < 2; ++rt)
#pragma unroll
        for (int kc = 0; kc < 8; ++kc)
            ktf[rt][kc] = *(const bhalf8*)&sKrow[(32 * wr + 16 * rt + ln) * KROW_S + kc * 32 + g * 8];

    float racc[2][4];
#pragma unroll
    for (int rt = 0; rt < 2; ++rt)
#pragma unroll
        for (int r = 0; r < 4; ++r) racc[rt][r] = 0.f;

    for (int js = js0; js < js1; ++js) {
        __syncthreads();
        stage_row(kb + (size_t)js * 64 * DD, sKrow, tid);
        __syncthreads();
        f32x4 aacc[2][2];
#pragma unroll
        for (int rt = 0; rt < 2; ++rt)
#pragma unroll
            for (int st = 0; st < 2; ++st) aacc[rt][st] = (f32x4){0.f, 0.f, 0.f, 0.f};
#pragma unroll
        for (int kc = 0; kc < 8; ++kc) {
            bhalf8 bf0 = *(const bhalf8*)&sKrow[(32 * wc + ln) * KROW_S + kc * 32 + g * 8];
            bhalf8 bf1 = *(const bhalf8*)&sKrow[(32 * wc + 16 + ln) * KROW_S + kc * 32 + g * 8];
#pragma unroll
            for (int rt = 0; rt < 2; ++rt) {
                aacc[rt][0] = mfma16(ktf[rt][kc], bf0, aacc[rt][0]);
                aacc[rt][1] = mfma16(ktf[rt][kc], bf1, aacc[rt][1]);
            }
        }
#pragma unroll
        for (int rt = 0; rt < 2; ++rt)
#pragma unroll
            for (int r = 0; r < 4; ++r) {
                int tg = it * 64 + 32 * wr + 16 * rt + g * 4 + r;
                float s = 0.f;
#pragma unroll
                for (int st = 0; st < 2; ++st) {
                    int sg_ = js * 64 + 32 * wc + 16 * st + ln;
                    float dv = aacc[rt][st][r];
                    float wgt = (sg_ < tg) ? 2.f : ((sg_ == tg) ? 1.f : 0.f);
                    s += wgt * dv * dv;
                }
                s += __shfl_xor(s, 1); s += __shfl_xor(s, 2);
                s += __shfl_xor(s, 4); s += __shfl_xor(s, 8);
                racc[rt][r] += s;
            }
    }
    if (ln == 0) {
#pragma unroll
        for (int rt = 0; rt < 2; ++rt)
#pragma unroll
            for (int r = 0; r < 4; ++r)
                atomicAdd(&rowterm[b * LL + it * 64 + 32 * wr + 16 * rt + g * 4 + r], racc[rt][r]);
    }
}

// ---- scan: inv[t] = 1/(sqrt(prefix_sum(rowterm)) + EPS) ---------------------
__global__ __launch_bounds__(256) void k_scan(const float* __restrict__ rowterm,
                                              float* __restrict__ inv) {
    int b = blockIdx.x, tid = threadIdx.x;
    __shared__ float sd[256];
    const float* rt = rowterm + b * LL;
    float v[8];
    float s = 0.f;
#pragma unroll
    for (int m = 0; m < 8; ++m) { v[m] = rt[tid * 8 + m]; s += v[m]; }
    sd[tid] = s;
    __syncthreads();
    for (int off = 1; off < 256; off <<= 1) {
        float add = (tid >= off) ? sd[tid - off] : 0.f;
        __syncthreads();
        sd[tid] += add;
        __syncthreads();
    }
    float run = sd[tid] - s;
#pragma unroll
    for (int m = 0; m < 8; ++m) {
        run += v[m];
        inv[b * LL + tid * 8 + m] = 1.f / (sqrtf(run) + EPS);
    }
}

// ---- main: O[t] = sum_{s<=t} (q_t.k_s) k_s  (atomic accum into qout) --------
__global__ __launch_bounds__(256, 2) void k_main(const float* __restrict__ qin,
                                                 const float* __restrict__ kin,
                                                 float* __restrict__ qout) {
    __shared__ __align__(16) unsigned short sKrow[64 * KROW_S];
    __shared__ __align__(16) unsigned short sKT[256 * KST_S];
    __shared__ __align__(16) unsigned short sAt[64 * AT_S];

    int bid = blockIdx.x;
    int b = bid / 80;
    int it, c; decode_chunk(bid % 80, it, c);
    int js0 = c * 8, js1 = (js0 + 8 < it + 1) ? js0 + 8 : it + 1;
    const float* qb = qin + (size_t)b * LL * DD;
    const float* kb = kin + (size_t)b * LL * DD;
    int tid = threadIdx.x, lane = tid & 63, w = tid >> 6;
    int wr = w >> 1, wc = w & 1, ln = lane & 15, g = lane >> 4;

    stage_row(qb + (size_t)it * 64 * DD, sKrow, tid);
    __syncthreads();
    bhalf8 qf[2][8];
#pragma unroll
    for (int rt = 0; rt < 2; ++rt)
#pragma unroll
        for (int kc = 0; kc < 8; ++kc)
            qf[rt][kc] = *(const bhalf8*)&sKrow[(32 * wr + 16 * rt + ln) * KROW_S + kc * 32 + g * 8];

    f32x4 oacc[2][8];
#pragma unroll
    for (int rt = 0; rt < 2; ++rt)
#pragma unroll
        for (int dt = 0; dt < 8; ++dt) oacc[rt][dt] = (f32x4){0.f, 0.f, 0.f, 0.f};

    for (int js = js0; js < js1; ++js) {
        __syncthreads();
        stage_dual(kb + (size_t)js * 64 * DD, sKrow, sKT, tid);
        __syncthreads();
        // ---- A = Q . Ks^T (64x64)
        f32x4 aacc[2][2];
#pragma unroll
        for (int rt = 0; rt < 2; ++rt)
#pragma unroll
            for (int st = 0; st < 2; ++st) aacc[rt][st] = (f32x4){0.f, 0.f, 0.f, 0.f};
#pragma unroll
        for (int kc = 0; kc < 8; ++kc) {
            bhalf8 bf0 = *(const bhalf8*)&sKrow[(32 * wc + ln) * KROW_S + kc * 32 + g * 8];
            bhalf8 bf1 = *(const bhalf8*)&sKrow[(32 * wc + 16 + ln) * KROW_S + kc * 32 + g * 8];
#pragma unroll
            for (int rt = 0; rt < 2; ++rt) {
                aacc[rt][0] = mfma16(qf[rt][kc], bf0, aacc[rt][0]);
                aacc[rt][1] = mfma16(qf[rt][kc], bf1, aacc[rt][1]);
            }
        }
        // ---- causal mask + bf16 -> sAt (transposition lanes->rows via LDS)
#pragma unroll
        for (int rt = 0; rt < 2; ++rt)
#pragma unroll
            for (int st = 0; st < 2; ++st)
#pragma unroll
                for (int r = 0; r < 4; ++r) {
                    int rloc = 32 * wr + 16 * rt + g * 4 + r;
                    int sloc = 32 * wc + 16 * st + ln;
                    float v = ((js * 64 + sloc) <= (it * 64 + rloc)) ? aacc[rt][st][r] : 0.f;
                    sAt[rloc * AT_S + sloc] = bf16of(v);
                }
        __syncthreads();
        // ---- O += A . Ks (64x256)
#pragma unroll
        for (int kc2 = 0; kc2 < 2; ++kc2) {
            bhalf8 af[2];
#pragma unroll
            for (int rt = 0; rt < 2; ++rt)
                af[rt] = *(const bhalf8*)&sAt[(32 * wr + 16 * rt + ln) * AT_S + kc2 * 32 + g * 8];
#pragma unroll
            for (int dt = 0; dt < 8; ++dt) {
                int d = 128 * wc + 16 * dt + ln;
                bhalf8 bf = *(const bhalf8*)&sKT[kst_off(d, kc2 * 32 + g * 8)];
#pragma unroll
                for (int rt = 0; rt < 2; ++rt)
                    oacc[rt][dt] = mfma16(af[rt], bf, oacc[rt][dt]);
            }
        }
    }
#pragma unroll
    for (int rt = 0; rt < 2; ++rt)
#pragma unroll
        for (int dt = 0; dt < 8; ++dt)
#pragma unroll
            for (int r = 0; r < 4; ++r) {
                size_t row = (size_t)b * LL + it * 64 + 32 * wr + 16 * rt + g * 4 + r;
                atomicAdd(&qout[row * DD + 128 * wc + 16 * dt + ln], oacc[rt][dt][r]);
            }
}

// ---- epilogue: qout = tanh(gain * O * inv) * scale (in place) ---------------
__global__ __launch_bounds__(256, 4) void k_epi(float* __restrict__ qout,
                                                const float* __restrict__ inv,
                                                const float* __restrict__ gain,
                                                const float* __restrict__ oscale) {
    int idx = blockIdx.x * 256 + threadIdx.x;   // f4 index
    int row = idx >> 6;
    int c4 = idx & 63;
    f4 o = ((const f4*)qout)[idx];
    float iv = inv[row];
    f4 g4 = ((const f4*)gain)[c4];
    f4 s4 = ((const f4*)oscale)[c4];
    f4 r;
#pragma unroll
    for (int e = 0; e < 4; ++e) r[e] = tanhf(g4[e] * (o[e] * iv)) * s4[e];
    ((f4*)qout)[idx] = r;
}

// ---- P_final = P_prev + K^T K (atomic accum over L-quarters) ----------------
__global__ __launch_bounds__(256, 2) void k_pfinal(const float* __restrict__ kin,
                                                   float* __restrict__ pout) {
    __shared__ __align__(16) unsigned short sKT[256 * KST_S];
    int bid = blockIdx.x;
    int b = bid >> 5;
    int slab = (bid >> 2) & 7;   // 32-row output slab
    int lq = bid & 3;            // L-quarter
    const float* kb = kin + (size_t)b * LL * DD;
    int tid = threadIdx.x, lane = tid & 63, w = tid >> 6;
    int ln = lane & 15, g = lane >> 4;
    f32x4 acc[2][4];
#pragma unroll
    for (int rt = 0; rt < 2; ++rt)
#pragma unroll
        for (int ct = 0; ct < 4; ++ct) acc[rt][ct] = (f32x4){0.f, 0.f, 0.f, 0.f};

    for (int ch = lq * 8; ch < lq * 8 + 8; ++ch) {
        __syncthreads();
#pragma unroll
        for (int iter = 0; iter < 4; ++iter) {
            int dq = (tid & 15) + 16 * iter;
            int sq = tid >> 4;
            const float* gs = kb + (size_t)(ch * 64 + 4 * sq) * DD + 4 * dq;
            f4 v0 = *(const f4*)(gs);
            f4 v1 = *(const f4*)(gs + DD);
            f4 v2 = *(const f4*)(gs + 2 * DD);
            f4 v3 = *(const f4*)(gs + 3 * DD);
#pragma unroll
            for (int i = 0; i < 4; ++i) {
                uint2 pv; pv.x = pack2(v0[i], v1[i]); pv.y = pack2(v2[i], v3[i]);
                *(uint2*)&sKT[kst_off(4 * dq + i, 4 * sq)] = pv;
            }
        }
        __syncthreads();
#pragma unroll
        for (int kc = 0; kc < 2; ++kc) {
            bhalf8 af[2];
#pragma unroll
            for (int rt = 0; rt < 2; ++rt)
                af[rt] = *(const bhalf8*)&sKT[kst_off(slab * 32 + 16 * rt + ln, kc * 32 + g * 8)];
#pragma unroll
            for (int ct = 0; ct < 4; ++ct) {
                bhalf8 bf = *(const bhalf8*)&sKT[kst_off(64 * w + 16 * ct + ln, kc * 32 + g * 8)];
#pragma unroll
                for (int rt = 0; rt < 2; ++rt)
                    acc[rt][ct] = mfma16(af[rt], bf, acc[rt][ct]);
            }
        }
    }
#pragma unroll
    for (int rt = 0; rt < 2; ++rt)
#pragma unroll
        for (int ct = 0; ct < 4; ++ct)
#pragma unroll
            for (int r = 0; r < 4; ++r) {
                int i = slab * 32 + 16 * rt + g * 4 + r;
                int j = 64 * w + 16 * ct + ln;
                atomicAdd(&pout[(size_t)b * DD * DD + (size_t)i * DD + j], acc[rt][ct][r]);
            }
}

extern "C" void kernel_launch(void* const* d_in, const int* in_sizes, int n_in,
                              void* d_out, int out_size, void* d_ws, size_t ws_size,
                              hipStream_t stream) {
    const float* q      = (const float*)d_in[0];
    const float* k      = (const float*)d_in[1];
    const float* pprev  = (const float*)d_in[2];
    const float* gain   = (const float*)d_in[3];
    const float* oscale = (const float*)d_in[4];
    float* qout = (float*)d_out;
    float* pout = qout + (size_t)NB * LL * DD;
    // rowterm/inv scratch lives in the P_final output region (overwritten last)
    float* rowterm = pout;
    float* inv     = pout + NB * LL;

    hipMemsetAsync(qout, 0, (size_t)NB * LL * DD * 4, stream);
    hipMemsetAsync(pout, 0, (size_t)2 * NB * LL * 4, stream);
    k_gram  <<<NB * 80, 256, 0, stream>>>(k, rowterm);
    k_scan  <<<NB,      256, 0, stream>>>(rowterm, inv);
    k_main  <<<NB * 80, 256, 0, stream>>>(q, k, qout);
    k_epi   <<<NB * LL * DD / 1024, 256, 0, stream>>>(qout, inv, gain, oscale);
    hipMemcpyAsync(pout, pprev, (size_t)NB * DD * DD * 4, hipMemcpyDeviceToDevice, stream);
    k_pfinal<<<128, 256, 0, stream>>>(k, pout);
}

// Round 3
// 105.583 us; speedup vs baseline: 8.8597x; 1.1706x over previous
//
#include <hip/hip_runtime.h>
#include <math.h>

#define NB 4
#define LL 2048
#define DD 256
#define EPS 1e-7f

typedef float f4 __attribute__((ext_vector_type(4)));
typedef __attribute__((ext_vector_type(8))) short bhalf8;   // 8 bf16 in 4 VGPRs
typedef __attribute__((ext_vector_type(4))) float f32x4;
typedef unsigned short ushort_t;

#define KROW_S 264   // fallback: row-major 64x256 bf16 tile stride
#define KST_S  72    // fallback: transposed tile stride
#define AT_S   72    // fallback: masked-A stride

// ---- helpers ----------------------------------------------------------------
__device__ __forceinline__ unsigned pack2(float lo, float hi) {
    unsigned ulo = __float_as_uint(lo) + 0x8000u;
    unsigned uhi = __float_as_uint(hi) + 0x8000u;
    return __builtin_amdgcn_perm(uhi, ulo, 0x07060302u);
}
__device__ __forceinline__ unsigned short bf16of(float x) {
    return (unsigned short)((__float_as_uint(x) + 0x8000u) >> 16);
}
__device__ __forceinline__ int kst_off(int d, int s) {
    return d * KST_S + (s ^ (((d >> 3) & 7) << 3));
}
__device__ __forceinline__ f32x4 mfma16(bhalf8 a, bhalf8 b, f32x4 c) {
    return __builtin_amdgcn_mfma_f32_16x16x32_bf16(a, b, c, 0, 0, 0);
}
__device__ __forceinline__ void decode_chunk(int e, int& it, int& c) {
    int i = 0, acc = 0;
    while (true) { int n = (i >> 3) + 1; if (acc + n > e) break; acc += n; ++i; }
    it = i; c = e - acc;
}
// async 16B global->LDS (dest = wave-uniform base + lane*16)
__device__ __forceinline__ void gll16(const ushort_t* gsrc, ushort_t* ldsbase) {
    __builtin_amdgcn_global_load_lds(
        (const __attribute__((address_space(1))) void*)gsrc,
        (__attribute__((address_space(3))) void*)ldsbase, 16, 0, 0);
}

// ============================ FAST PATH ======================================
// ws layout: Qbf[b][L][D], Kbf[b][L][D], KTbf[b][D][L] (bf16), rowterm, inv

__global__ __launch_bounds__(256) void k_convQ(const float* __restrict__ in,
                                               ushort_t* __restrict__ out) {
    int idx = blockIdx.x * 256 + threadIdx.x;   // 8 elems per thread
    f4 a = ((const f4*)in)[idx * 2];
    f4 b = ((const f4*)in)[idx * 2 + 1];
    uint4 o;
    o.x = pack2(a[0], a[1]); o.y = pack2(a[2], a[3]);
    o.z = pack2(b[0], b[1]); o.w = pack2(b[2], b[3]);
    ((uint4*)out)[idx] = o;
}

__global__ __launch_bounds__(256) void k_convK(const float* __restrict__ kin,
                                               ushort_t* __restrict__ krow,
                                               ushort_t* __restrict__ kt) {
    int bid = blockIdx.x;                 // b(4) x stile(32) x dtile(4)
    int b = bid >> 7, st = (bid >> 2) & 31, dt = bid & 3;
    __shared__ float T[64][65];
    int tid = threadIdx.x;
    const float* src = kin + ((size_t)(b * LL + st * 64)) * DD + dt * 64;
#pragma unroll
    for (int p = 0; p < 4; ++p) {
        int r = p * 16 + (tid >> 4), c = (tid & 15) * 4;
        f4 v = *(const f4*)(src + (size_t)r * DD + c);
        T[r][c] = v[0]; T[r][c+1] = v[1]; T[r][c+2] = v[2]; T[r][c+3] = v[3];
    }
    __syncthreads();
#pragma unroll
    for (int p = 0; p < 2; ++p) {         // row-major mirror
        int r = p * 32 + (tid >> 3), c = (tid & 7) * 8;
        uint4 o;
        o.x = pack2(T[r][c], T[r][c+1]);   o.y = pack2(T[r][c+2], T[r][c+3]);
        o.z = pack2(T[r][c+4], T[r][c+5]); o.w = pack2(T[r][c+6], T[r][c+7]);
        *(uint4*)(krow + ((size_t)(b * LL + st * 64 + r)) * DD + dt * 64 + c) = o;
    }
#pragma unroll
    for (int p = 0; p < 2; ++p) {         // transposed mirror
        int d = p * 32 + (tid >> 3), c = (tid & 7) * 8;
        uint4 o;
        o.x = pack2(T[c][d], T[c+1][d]);   o.y = pack2(T[c+2][d], T[c+3][d]);
        o.z = pack2(T[c+4][d], T[c+5][d]); o.w = pack2(T[c+6][d], T[c+7][d]);
        *(uint4*)(kt + ((size_t)(b * DD + dt * 64 + d)) * LL + st * 64 + c) = o;
    }
}

#define CH32 16   // js32 steps per chunk

// fused: A=Q.K^T (masked) -> O = A.K, and G=K.K^T -> rowterm, one pass.
__global__ __launch_bounds__(256, 2) void k_fused(const ushort_t* __restrict__ Qbf,
                                                  const ushort_t* __restrict__ Kbf,
                                                  const ushort_t* __restrict__ KTbf,
                                                  float* __restrict__ qout,
                                                  float* __restrict__ rowterm) {
    // LDS bytes: [0,16K) sKrow[32][256]; [16K,32K) sKT0[256][32]; [32K,48K) sKT1; [48K,52K) sAt[64][32]
    __shared__ __align__(16) ushort_t lds[26624];
    ushort_t* sKrow = lds;
    ushort_t* sKT0  = lds + 8192;
    ushort_t* sKT1  = lds + 16384;
    ushort_t* sAt   = lds + 24576;
    ushort_t* sBig  = lds + 8192;     // 32KB staging for Q_it/K_it (overlaps sKT0/1)

    int bid = blockIdx.x;
    int b = bid / 80;
    int it, c; decode_chunk(bid % 80, it, c);
    int j0 = c * CH32;
    int j1 = j0 + CH32; { int lim = 2 * (it + 1); if (j1 > lim) j1 = lim; }
    const ushort_t* Qb  = Qbf  + (size_t)b * LL * DD;
    const ushort_t* Kb  = Kbf  + (size_t)b * LL * DD;
    const ushort_t* KTb = KTbf + (size_t)b * DD * LL;
    int tid = threadIdx.x, lane = tid & 63, w = tid >> 6;
    int wr = w >> 1, wc = w & 1, ln = lane & 15, g = lane >> 4;

    // ---- prologue: stage Q_it then K_it (64x256) into sBig, extract frags
    bhalf8 qf[2][8], ktf[2][8];
#pragma unroll
    for (int pass = 0; pass < 2; ++pass) {
        const ushort_t* gt = (pass == 0 ? Qb : Kb) + (size_t)it * 64 * DD;
#pragma unroll
        for (int cl = 0; cl < 8; ++cl) {
            int row = w * 16 + cl * 2 + (lane >> 5);
            int u = lane & 31;
            gll16(gt + (size_t)row * DD + ((u ^ (row & 7)) * 8),
                  sBig + (w * 16 + cl * 2) * DD);
        }
        __syncthreads();   // drains vmcnt
#pragma unroll
        for (int rt = 0; rt < 2; ++rt)
#pragma unroll
            for (int kc = 0; kc < 8; ++kc) {
                int row = 32 * wr + 16 * rt + ln;
                bhalf8 v = *(const bhalf8*)&sBig[row * DD + (((kc * 4 + g) ^ (row & 7)) * 8)];
                if (pass == 0) qf[rt][kc] = v; else ktf[rt][kc] = v;
            }
        __syncthreads();   // frags extracted; sBig reusable
    }

    // ---- issue first js loads
    {
        int j = j0;
#pragma unroll
        for (int cl = 0; cl < 4; ++cl) {   // sKrow: rows K[j*32 .. +32)
            int row = w * 8 + cl * 2 + (lane >> 5);
            int u = lane & 31;
            gll16(Kb + (size_t)(j * 32 + row) * DD + ((u ^ (row & 7)) * 8),
                  sKrow + (w * 8 + cl * 2) * DD);
        }
#pragma unroll
        for (int cl = 0; cl < 4; ++cl) {   // sKT0: [256][32]
            int d = w * 64 + cl * 16 + (lane >> 2);
            int u = lane & 3;
            gll16(KTb + (size_t)d * LL + j * 32 + ((u ^ (d & 3)) * 8),
                  sKT0 + (w * 64 + cl * 16) * 32);
        }
    }

    f32x4 oacc[2][8];
#pragma unroll
    for (int rt = 0; rt < 2; ++rt)
#pragma unroll
        for (int dt = 0; dt < 8; ++dt) oacc[rt][dt] = (f32x4){0.f, 0.f, 0.f, 0.f};
    float racc[2][4];
#pragma unroll
    for (int rt = 0; rt < 2; ++rt)
#pragma unroll
        for (int r = 0; r < 4; ++r) racc[rt][r] = 0.f;

    int buf = 0;
    for (int j = j0; j < j1; ++j) {
        __syncthreads();   // compiler emits vmcnt(0) drain: sKrow/sKT[buf] landed for all waves
        ushort_t* skt = buf ? sKT1 : sKT0;
        ushort_t* sktN = buf ? sKT0 : sKT1;
        // ---- A_q and G share B-fragments (rows of K_js)
        f32x4 qa[2], ga[2];
#pragma unroll
        for (int rt = 0; rt < 2; ++rt) { qa[rt] = (f32x4){0.f,0.f,0.f,0.f}; ga[rt] = (f32x4){0.f,0.f,0.f,0.f}; }
#pragma unroll
        for (int kc = 0; kc < 8; ++kc) {
            int srow = 16 * wc + ln;
            bhalf8 bf = *(const bhalf8*)&sKrow[srow * DD + (((kc * 4 + g) ^ (srow & 7)) * 8)];
#pragma unroll
            for (int rt = 0; rt < 2; ++rt) {
                qa[rt] = mfma16(qf[rt][kc], bf, qa[rt]);
                ga[rt] = mfma16(ktf[rt][kc], bf, ga[rt]);
            }
        }
        // ---- mask A -> sAt (swizzled); accumulate G into per-lane racc
        int sg0 = j * 32 + 16 * wc + ln;
        int sloc_u = (2 * wc + (ln >> 3));
#pragma unroll
        for (int rt = 0; rt < 2; ++rt)
#pragma unroll
            for (int r = 0; r < 4; ++r) {
                int tloc = 32 * wr + 16 * rt + g * 4 + r;
                int tg = it * 64 + tloc;
                float av = (sg0 <= tg) ? qa[rt][r] : 0.f;
                sAt[tloc * 32 + ((sloc_u ^ (tloc & 3)) * 8) + (ln & 7)] = bf16of(av);
                float gv = ga[rt][r];
                float wgt = (sg0 < tg) ? 2.f : ((sg0 == tg) ? 1.f : 0.f);
                racc[rt][r] = fmaf(wgt * gv, gv, racc[rt][r]);
            }
        __syncthreads();   // sAt ready; sKrow consumed by all waves
        // ---- issue next js loads (land checked at next loop-head barrier)
        if (j + 1 < j1) {
            int jn = j + 1;
#pragma unroll
            for (int cl = 0; cl < 4; ++cl) {
                int row = w * 8 + cl * 2 + (lane >> 5);
                int u = lane & 31;
                gll16(Kb + (size_t)(jn * 32 + row) * DD + ((u ^ (row & 7)) * 8),
                      sKrow + (w * 8 + cl * 2) * DD);
            }
#pragma unroll
            for (int cl = 0; cl < 4; ++cl) {
                int d = w * 64 + cl * 16 + (lane >> 2);
                int u = lane & 3;
                gll16(KTb + (size_t)d * LL + jn * 32 + ((u ^ (d & 3)) * 8),
                      sktN + (w * 64 + cl * 16) * 32);
            }
        }
        // ---- O += A . K_js   (reads sAt + sKT[buf])
        bhalf8 af[2];
#pragma unroll
        for (int rt = 0; rt < 2; ++rt) {
            int tr = 32 * wr + 16 * rt + ln;
            af[rt] = *(const bhalf8*)&sAt[tr * 32 + ((g ^ (tr & 3)) * 8)];
        }
#pragma unroll
        for (int dt = 0; dt < 8; ++dt) {
            int d = 128 * wc + 16 * dt + ln;
            bhalf8 bk = *(const bhalf8*)&skt[d * 32 + ((g ^ (d & 3)) * 8)];
#pragma unroll
            for (int rt = 0; rt < 2; ++rt)
                oacc[rt][dt] = mfma16(af[rt], bk, oacc[rt][dt]);
        }
        buf ^= 1;
    }
    // ---- epilogue: atomics
#pragma unroll
    for (int rt = 0; rt < 2; ++rt)
#pragma unroll
        for (int dt = 0; dt < 8; ++dt)
#pragma unroll
            for (int r = 0; r < 4; ++r) {
                size_t row = (size_t)b * LL + it * 64 + 32 * wr + 16 * rt + g * 4 + r;
                atomicAdd(&qout[row * DD + 128 * wc + 16 * dt + ln], oacc[rt][dt][r]);
            }
#pragma unroll
    for (int rt = 0; rt < 2; ++rt)
#pragma unroll
        for (int r = 0; r < 4; ++r) {
            float v = racc[rt][r];
            v += __shfl_xor(v, 1); v += __shfl_xor(v, 2);
            v += __shfl_xor(v, 4); v += __shfl_xor(v, 8);
            if (ln == 0)
                atomicAdd(&rowterm[b * LL + it * 64 + 32 * wr + 16 * rt + g * 4 + r], v);
        }
}

// P_final partial: pout += K^T K over one L-quarter (reads KT mirror)
__global__ __launch_bounds__(256, 2) void k_pfinal2(const ushort_t* __restrict__ KTbf,
                                                    float* __restrict__ pout) {
    __shared__ __align__(16) ushort_t sT[256 * 64];   // [256][64] 32KB
    int bid = blockIdx.x;
    int b = bid >> 5, slab = (bid >> 2) & 7, lq = bid & 3;
    const ushort_t* KTb = KTbf + (size_t)b * DD * LL;
    int tid = threadIdx.x, lane = tid & 63, w = tid >> 6;
    int ln = lane & 15, g = lane >> 4;
    f32x4 acc[2][4];
#pragma unroll
    for (int rt = 0; rt < 2; ++rt)
#pragma unroll
        for (int ct = 0; ct < 4; ++ct) acc[rt][ct] = (f32x4){0.f, 0.f, 0.f, 0.f};

    for (int ch = lq * 8; ch < lq * 8 + 8; ++ch) {
        __syncthreads();
#pragma unroll
        for (int cl = 0; cl < 8; ++cl) {
            int d = w * 64 + cl * 8 + (lane >> 3);
            int u = lane & 7;
            gll16(KTb + (size_t)d * LL + ch * 64 + ((u ^ (d & 7)) * 8),
                  sT + (w * 64 + cl * 8) * 64);
        }
        __syncthreads();   // vmcnt drained by compiler before barrier
#pragma unroll
        for (int kc = 0; kc < 2; ++kc) {
            bhalf8 af[2];
#pragma unroll
            for (int rt = 0; rt < 2; ++rt) {
                int dr = slab * 32 + 16 * rt + ln;
                af[rt] = *(const bhalf8*)&sT[dr * 64 + (((kc * 4 + g) ^ (dr & 7)) * 8)];
            }
#pragma unroll
            for (int ct = 0; ct < 4; ++ct) {
                int dc = w * 64 + 16 * ct + ln;
                bhalf8 bf = *(const bhalf8*)&sT[dc * 64 + (((kc * 4 + g) ^ (dc & 7)) * 8)];
#pragma unroll
                for (int rt = 0; rt < 2; ++rt)
                    acc[rt][ct] = mfma16(af[rt], bf, acc[rt][ct]);
            }
        }
    }
#pragma unroll
    for (int rt = 0; rt < 2; ++rt)
#pragma unroll
        for (int ct = 0; ct < 4; ++ct)
#pragma unroll
            for (int r = 0; r < 4; ++r) {
                int i = slab * 32 + 16 * rt + g * 4 + r;
                int j = w * 64 + 16 * ct + ln;
                atomicAdd(&pout[(size_t)b * DD * DD + (size_t)i * DD + j], acc[rt][ct][r]);
            }
}

// ---- scan + epilogue (shared by both paths) ---------------------------------
__global__ __launch_bounds__(256) void k_scan(const float* __restrict__ rowterm,
                                              float* __restrict__ inv) {
    int b = blockIdx.x, tid = threadIdx.x;
    __shared__ float sd[256];
    const float* rt = rowterm + b * LL;
    float v[8];
    float s = 0.f;
#pragma unroll
    for (int m = 0; m < 8; ++m) { v[m] = rt[tid * 8 + m]; s += v[m]; }
    sd[tid] = s;
    __syncthreads();
    for (int off = 1; off < 256; off <<= 1) {
        float add = (tid >= off) ? sd[tid - off] : 0.f;
        __syncthreads();
        sd[tid] += add;
        __syncthreads();
    }
    float run = sd[tid] - s;
#pragma unroll
    for (int m = 0; m < 8; ++m) {
        run += v[m];
        inv[b * LL + tid * 8 + m] = 1.f / (sqrtf(run) + EPS);
    }
}

__global__ __launch_bounds__(256, 4) void k_epi(float* __restrict__ qout,
                                                const float* __restrict__ inv,
                                                const float* __restrict__ gain,
                                                const float* __restrict__ oscale) {
    int idx = blockIdx.x * 256 + threadIdx.x;
    int row = idx >> 6;
    int c4 = idx & 63;
    f4 o = ((const f4*)qout)[idx];
    float iv = inv[row];
    f4 g4 = ((const f4*)gain)[c4];
    f4 s4 = ((const f4*)oscale)[c4];
    f4 r;
#pragma unroll
    for (int e = 0; e < 4; ++e) r[e] = tanhf(g4[e] * (o[e] * iv)) * s4[e];
    ((f4*)qout)[idx] = r;
}

// ============================ FALLBACK (round-2, validated) ==================
__device__ __forceinline__ void stage_row(const float* __restrict__ g,
                                          unsigned short* krow, int tid) {
#pragma unroll
    for (int m = 0; m < 16; ++m) {
        int row = m * 4 + (tid >> 6);
        int c4 = tid & 63;
        f4 v = *(const f4*)(g + (size_t)row * DD + c4 * 4);
        uint2 pv; pv.x = pack2(v[0], v[1]); pv.y = pack2(v[2], v[3]);
        *(uint2*)&krow[row * KROW_S + c4 * 4] = pv;
    }
}
__device__ __forceinline__ void stage_dual(const float* __restrict__ g,
                                           unsigned short* krow,
                                           unsigned short* kst, int tid) {
#pragma unroll
    for (int iter = 0; iter < 4; ++iter) {
        int dq = (tid & 15) + 16 * iter;
        int sq = tid >> 4;
        const float* gs = g + (size_t)(4 * sq) * DD + 4 * dq;
        f4 v0 = *(const f4*)(gs);
        f4 v1 = *(const f4*)(gs + DD);
        f4 v2 = *(const f4*)(gs + 2 * DD);
        f4 v3 = *(const f4*)(gs + 3 * DD);
        {
            uint2 p0; p0.x = pack2(v0[0], v0[1]); p0.y = pack2(v0[2], v0[3]);
            *(uint2*)&krow[(4 * sq + 0) * KROW_S + 4 * dq] = p0;
            uint2 p1; p1.x = pack2(v1[0], v1[1]); p1.y = pack2(v1[2], v1[3]);
            *(uint2*)&krow[(4 * sq + 1) * KROW_S + 4 * dq] = p1;
            uint2 p2; p2.x = pack2(v2[0], v2[1]); p2.y = pack2(v2[2], v2[3]);
            *(uint2*)&krow[(4 * sq + 2) * KROW_S + 4 * dq] = p2;
            uint2 p3; p3.x = pack2(v3[0], v3[1]); p3.y = pack2(v3[2], v3[3]);
            *(uint2*)&krow[(4 * sq + 3) * KROW_S + 4 * dq] = p3;
        }
#pragma unroll
        for (int i = 0; i < 4; ++i) {
            uint2 pv; pv.x = pack2(v0[i], v1[i]); pv.y = pack2(v2[i], v3[i]);
            *(uint2*)&kst[kst_off(4 * dq + i, 4 * sq)] = pv;
        }
    }
}
__global__ __launch_bounds__(256, 2) void k_gram(const float* __restrict__ kin,
                                                 float* __restrict__ rowterm) {
    __shared__ __align__(16) unsigned short sKrow[64 * KROW_S];
    int bid = blockIdx.x;
    int b = bid / 80;
    int it, c; decode_chunk(bid % 80, it, c);
    int js0 = c * 8, js1 = (js0 + 8 < it + 1) ? js0 + 8 : it + 1;
    const float* kb = kin + (size_t)b * LL * DD;
    int tid = threadIdx.x, lane = tid & 63, w = tid >> 6;
    int wr = w >> 1, wc = w & 1, ln = lane & 15, g = lane >> 4;
    stage_row(kb + (size_t)it * 64 * DD, sKrow, tid);
    __syncthreads();
    bhalf8 ktf[2][8];
#pragma unroll
    for (int rt = 0; rt < 2; ++rt)
#pragma unroll
        for (int kc = 0; kc < 8; ++kc)
            ktf[rt][kc] = *(const bhalf8*)&sKrow[(32 * wr + 16 * rt + ln) * KROW_S + kc * 32 + g * 8];
    float racc[2][4];
#pragma unroll
    for (int rt = 0; rt < 2; ++rt)
#pragma unroll
        for (int r = 0; r < 4; ++r) racc[rt][r] = 0.f;
    for (int js = js0; js < js1; ++js) {
        __syncthreads();
        stage_row(kb + (size_t)js * 64 * DD, sKrow, tid);
        __syncthreads();
        f32x4 aacc[2][2];
#pragma unroll
        for (int rt = 0; rt < 2; ++rt)
#pragma unroll
            for (int st = 0; st < 2; ++st) aacc[rt][st] = (f32x4){0.f, 0.f, 0.f, 0.f};
#pragma unroll
        for (int kc = 0; kc < 8; ++kc) {
            bhalf8 bf0 = *(const bhalf8*)&sKrow[(32 * wc + ln) * KROW_S + kc * 32 + g * 8];
            bhalf8 bf1 = *(const bhalf8*)&sKrow[(32 * wc + 16 + ln) * KROW_S + kc * 32 + g * 8];
#pragma unroll
            for (int rt = 0; rt < 2; ++rt) {
                aacc[rt][0] = mfma16(ktf[rt][kc], bf0, aacc[rt][0]);
                aacc[rt][1] = mfma16(ktf[rt][kc], bf1, aacc[rt][1]);
            }
        }
#pragma unroll
        for (int rt = 0; rt < 2; ++rt)
#pragma unroll
            for (int r = 0; r < 4; ++r) {
                int tg = it * 64 + 32 * wr + 16 * rt + g * 4 + r;
                float s = 0.f;
#pragma unroll
                for (int st = 0; st < 2; ++st) {
                    int sg_ = js * 64 + 32 * wc + 16 * st + ln;
                    float dv = aacc[rt][st][r];
                    float wgt = (sg_ < tg) ? 2.f : ((sg_ == tg) ? 1.f : 0.f);
                    s += wgt * dv * dv;
                }
                racc[rt][r] += s;
            }
    }
#pragma unroll
    for (int rt = 0; rt < 2; ++rt)
#pragma unroll
        for (int r = 0; r < 4; ++r) {
            float v = racc[rt][r];
            v += __shfl_xor(v, 1); v += __shfl_xor(v, 2);
            v += __shfl_xor(v, 4); v += __shfl_xor(v, 8);
            if (ln == 0)
                atomicAdd(&rowterm[b * LL + it * 64 + 32 * wr + 16 * rt + g * 4 + r], v);
        }
}
__global__ __launch_bounds__(256, 2) void k_main(const float* __restrict__ qin,
                                                 const float* __restrict__ kin,
                                                 float* __restrict__ qout) {
    __shared__ __align__(16) unsigned short sKrow[64 * KROW_S];
    __shared__ __align__(16) unsigned short sKT[256 * KST_S];
    __shared__ __align__(16) unsigned short sAt[64 * AT_S];
    int bid = blockIdx.x;
    int b = bid / 80;
    int it, c; decode_chunk(bid % 80, it, c);
    int js0 = c * 8, js1 = (js0 + 8 < it + 1) ? js0 + 8 : it + 1;
    const float* qb = qin + (size_t)b * LL * DD;
    const float* kb = kin + (size_t)b * LL * DD;
    int tid = threadIdx.x, lane = tid & 63, w = tid >> 6;
    int wr = w >> 1, wc = w & 1, ln = lane & 15, g = lane >> 4;
    stage_row(qb + (size_t)it * 64 * DD, sKrow, tid);
    __syncthreads();
    bhalf8 qf[2][8];
#pragma unroll
    for (int rt = 0; rt < 2; ++rt)
#pragma unroll
        for (int kc = 0; kc < 8; ++kc)
            qf[rt][kc] = *(const bhalf8*)&sKrow[(32 * wr + 16 * rt + ln) * KROW_S + kc * 32 + g * 8];
    f32x4 oacc[2][8];
#pragma unroll
    for (int rt = 0; rt < 2; ++rt)
#pragma unroll
        for (int dt = 0; dt < 8; ++dt) oacc[rt][dt] = (f32x4){0.f, 0.f, 0.f, 0.f};
    for (int js = js0; js < js1; ++js) {
        __syncthreads();
        stage_dual(kb + (size_t)js * 64 * DD, sKrow, sKT, tid);
        __syncthreads();
        f32x4 aacc[2][2];
#pragma unroll
        for (int rt = 0; rt < 2; ++rt)
#pragma unroll
            for (int st = 0; st < 2; ++st) aacc[rt][st] = (f32x4){0.f, 0.f, 0.f, 0.f};
#pragma unroll
        for (int kc = 0; kc < 8; ++kc) {
            bhalf8 bf0 = *(const bhalf8*)&sKrow[(32 * wc + ln) * KROW_S + kc * 32 + g * 8];
            bhalf8 bf1 = *(const bhalf8*)&sKrow[(32 * wc + 16 + ln) * KROW_S + kc * 32 + g * 8];
#pragma unroll
            for (int rt = 0; rt < 2; ++rt) {
                aacc[rt][0] = mfma16(qf[rt][kc], bf0, aacc[rt][0]);
                aacc[rt][1] = mfma16(qf[rt][kc], bf1, aacc[rt][1]);
            }
        }
#pragma unroll
        for (int rt = 0; rt < 2; ++rt)
#pragma unroll
            for (int st = 0; st < 2; ++st)
#pragma unroll
                for (int r = 0; r < 4; ++r) {
                    int rloc = 32 * wr + 16 * rt + g * 4 + r;
                    int sloc = 32 * wc + 16 * st + ln;
                    float v = ((js * 64 + sloc) <= (it * 64 + rloc)) ? aacc[rt][st][r] : 0.f;
                    sAt[rloc * AT_S + sloc] = bf16of(v);
                }
        __syncthreads();
#pragma unroll
        for (int kc2 = 0; kc2 < 2; ++kc2) {
            bhalf8 af[2];
#pragma unroll
            for (int rt = 0; rt < 2; ++rt)
                af[rt] = *(const bhalf8*)&sAt[(32 * wr + 16 * rt + ln) * AT_S + kc2 * 32 + g * 8];
#pragma unroll
            for (int dt = 0; dt < 8; ++dt) {
                int d = 128 * wc + 16 * dt + ln;
                bhalf8 bf = *(const bhalf8*)&sKT[kst_off(d, kc2 * 32 + g * 8)];
#pragma unroll
                for (int rt = 0; rt < 2; ++rt)
                    oacc[rt][dt] = mfma16(af[rt], bf, oacc[rt][dt]);
            }
        }
    }
#pragma unroll
    for (int rt = 0; rt < 2; ++rt)
#pragma unroll
        for (int dt = 0; dt < 8; ++dt)
#pragma unroll
            for (int r = 0; r < 4; ++r) {
                size_t row = (size_t)b * LL + it * 64 + 32 * wr + 16 * rt + g * 4 + r;
                atomicAdd(&qout[row * DD + 128 * wc + 16 * dt + ln], oacc[rt][dt][r]);
            }
}
__global__ __launch_bounds__(256, 2) void k_pfinal(const float* __restrict__ kin,
                                                   float* __restrict__ pout) {
    __shared__ __align__(16) unsigned short sKT[256 * KST_S];
    int bid = blockIdx.x;
    int b = bid >> 5;
    int slab = (bid >> 2) & 7;
    int lq = bid & 3;
    const float* kb = kin + (size_t)b * LL * DD;
    int tid = threadIdx.x, lane = tid & 63, w = tid >> 6;
    int ln = lane & 15, g = lane >> 4;
    f32x4 acc[2][4];
#pragma unroll
    for (int rt = 0; rt < 2; ++rt)
#pragma unroll
        for (int ct = 0; ct < 4; ++ct) acc[rt][ct] = (f32x4){0.f, 0.f, 0.f, 0.f};
    for (int ch = lq * 8; ch < lq * 8 + 8; ++ch) {
        __syncthreads();
#pragma unroll
        for (int iter = 0; iter < 4; ++iter) {
            int dq = (tid & 15) + 16 * iter;
            int sq = tid >> 4;
            const float* gs = kb + (size_t)(ch * 64 + 4 * sq) * DD + 4 * dq;
            f4 v0 = *(const f4*)(gs);
            f4 v1 = *(const f4*)(gs + DD);
            f4 v2 = *(const f4*)(gs + 2 * DD);
            f4 v3 = *(const f4*)(gs + 3 * DD);
#pragma unroll
            for (int i = 0; i < 4; ++i) {
                uint2 pv; pv.x = pack2(v0[i], v1[i]); pv.y = pack2(v2[i], v3[i]);
                *(uint2*)&sKT[kst_off(4 * dq + i, 4 * sq)] = pv;
            }
        }
        __syncthreads();
#pragma unroll
        for (int kc = 0; kc < 2; ++kc) {
            bhalf8 af[2];
#pragma unroll
            for (int rt = 0; rt < 2; ++rt)
                af[rt] = *(const bhalf8*)&sKT[kst_off(slab * 32 + 16 * rt + ln, kc * 32 + g * 8)];
#pragma unroll
            for (int ct = 0; ct < 4; ++ct) {
                bhalf8 bf = *(const bhalf8*)&sKT[kst_off(64 * w + 16 * ct + ln, kc * 32 + g * 8)];
#pragma unroll
                for (int rt = 0; rt < 2; ++rt)
                    acc[rt][ct] = mfma16(af[rt], bf, acc[rt][ct]);
            }
        }
    }
#pragma unroll
    for (int rt = 0; rt < 2; ++rt)
#pragma unroll
        for (int ct = 0; ct < 4; ++ct)
#pragma unroll
            for (int r = 0; r < 4; ++r) {
                int i = slab * 32 + 16 * rt + g * 4 + r;
                int j = 64 * w + 16 * ct + ln;
                atomicAdd(&pout[(size_t)b * DD * DD + (size_t)i * DD + j], acc[rt][ct][r]);
            }
}

// ============================ launch =========================================
extern "C" void kernel_launch(void* const* d_in, const int* in_sizes, int n_in,
                              void* d_out, int out_size, void* d_ws, size_t ws_size,
                              hipStream_t stream) {
    const float* q      = (const float*)d_in[0];
    const float* k      = (const float*)d_in[1];
    const float* pprev  = (const float*)d_in[2];
    const float* gain   = (const float*)d_in[3];
    const float* oscale = (const float*)d_in[4];
    float* qout = (float*)d_out;
    float* pout = qout + (size_t)NB * LL * DD;

    size_t mirror_elems = (size_t)NB * LL * DD;           // per mirror
    size_t need = mirror_elems * 2 * 3 + (size_t)2 * NB * LL * 4;  // 12MB + 64KB

    if (ws_size >= need) {
        ushort_t* Qbf  = (ushort_t*)d_ws;
        ushort_t* Kbf  = Qbf + mirror_elems;
        ushort_t* KTbf = Kbf + mirror_elems;
        float* rowterm = (float*)(KTbf + mirror_elems);
        float* invp    = rowterm + NB * LL;

        hipMemsetAsync(qout, 0, (size_t)NB * LL * DD * 4, stream);
        hipMemsetAsync(rowterm, 0, (size_t)NB * LL * 4, stream);
        k_convQ  <<<NB * LL * DD / 2048, 256, 0, stream>>>(q, Qbf);
        k_convK  <<<512, 256, 0, stream>>>(k, Kbf, KTbf);
        k_fused  <<<NB * 80, 256, 0, stream>>>(Qbf, Kbf, KTbf, qout, rowterm);
        k_scan   <<<NB, 256, 0, stream>>>(rowterm, invp);
        k_epi    <<<NB * LL * DD / 1024, 256, 0, stream>>>(qout, invp, gain, oscale);
        hipMemcpyAsync(pout, pprev, (size_t)NB * DD * DD * 4, hipMemcpyDeviceToDevice, stream);
        k_pfinal2<<<128, 256, 0, stream>>>(KTbf, pout);
    } else {
        float* rowterm = pout;
        float* invp    = pout + NB * LL;
        hipMemsetAsync(qout, 0, (size_t)NB * LL * DD * 4, stream);
        hipMemsetAsync(pout, 0, (size_t)2 * NB * LL * 4, stream);
        k_gram  <<<NB * 80, 256, 0, stream>>>(k, rowterm);
        k_scan  <<<NB, 256, 0, stream>>>(rowterm, invp);
        k_main  <<<NB * 80, 256, 0, stream>>>(q, k, qout);
        k_epi   <<<NB * LL * DD / 1024, 256, 0, stream>>>(qout, invp, gain, oscale);
        hipMemcpyAsync(pout, pprev, (size_t)NB * DD * DD * 4, hipMemcpyDeviceToDevice, stream);
        k_pfinal<<<128, 256, 0, stream>>>(k, pout);
    }
}

// Round 4
// 93.517 us; speedup vs baseline: 10.0028x; 1.1290x over previous
//
#include <hip/hip_runtime.h>
#include <math.h>

#define NB 4
#define LL 2048
#define DD 256
#define EPS 1e-7f

typedef float f4 __attribute__((ext_vector_type(4)));
typedef __attribute__((ext_vector_type(8))) short bhalf8;   // 8 bf16 in 4 VGPRs
typedef __attribute__((ext_vector_type(4))) float f32x4;
typedef unsigned short ushort_t;

#define KROW_S 264   // fallback strides
#define KST_S  72
#define AT_S   72

// ---- helpers ----------------------------------------------------------------
__device__ __forceinline__ unsigned pack2(float lo, float hi) {
    unsigned ulo = __float_as_uint(lo) + 0x8000u;
    unsigned uhi = __float_as_uint(hi) + 0x8000u;
    return __builtin_amdgcn_perm(uhi, ulo, 0x07060302u);
}
__device__ __forceinline__ unsigned short bf16of(float x) {
    return (unsigned short)((__float_as_uint(x) + 0x8000u) >> 16);
}
__device__ __forceinline__ int kst_off(int d, int s) {
    return d * KST_S + (s ^ (((d >> 3) & 7) << 3));
}
__device__ __forceinline__ f32x4 mfma16(bhalf8 a, bhalf8 b, f32x4 c) {
    return __builtin_amdgcn_mfma_f32_16x16x32_bf16(a, b, c, 0, 0, 0);
}
__device__ __forceinline__ void gll16(const ushort_t* gsrc, ushort_t* ldsbase) {
    __builtin_amdgcn_global_load_lds(
        (const __attribute__((address_space(1))) void*)gsrc,
        (__attribute__((address_space(3))) void*)ldsbase, 16, 0, 0);
}

// ============================ FAST PATH ======================================
// ws: Kbf[b][L][D], KTbf[b][D][L] (bf16), rowterm, inv

__global__ __launch_bounds__(256) void k_convK(const float* __restrict__ kin,
                                               ushort_t* __restrict__ krow,
                                               ushort_t* __restrict__ kt,
                                               float* __restrict__ rowterm) {
    int bid = blockIdx.x;                 // b(4) x stile(32) x dtile(4)
    int b = bid >> 7, st = (bid >> 2) & 31, dt = bid & 3;
    __shared__ float T[64][65];
    int tid = threadIdx.x;
    if (bid < 8) {                        // zero rowterm (8192 floats) for atomics
#pragma unroll
        for (int m = 0; m < 4; ++m) rowterm[bid * 1024 + m * 256 + tid] = 0.f;
    }
    const float* src = kin + ((size_t)(b * LL + st * 64)) * DD + dt * 64;
#pragma unroll
    for (int p = 0; p < 4; ++p) {
        int r = p * 16 + (tid >> 4), c = (tid & 15) * 4;
        f4 v = *(const f4*)(src + (size_t)r * DD + c);
        T[r][c] = v[0]; T[r][c+1] = v[1]; T[r][c+2] = v[2]; T[r][c+3] = v[3];
    }
    __syncthreads();
#pragma unroll
    for (int p = 0; p < 2; ++p) {         // row-major mirror
        int r = p * 32 + (tid >> 3), c = (tid & 7) * 8;
        uint4 o;
        o.x = pack2(T[r][c], T[r][c+1]);   o.y = pack2(T[r][c+2], T[r][c+3]);
        o.z = pack2(T[r][c+4], T[r][c+5]); o.w = pack2(T[r][c+6], T[r][c+7]);
        *(uint4*)(krow + ((size_t)(b * LL + st * 64 + r)) * DD + dt * 64 + c) = o;
    }
#pragma unroll
    for (int p = 0; p < 2; ++p) {         // transposed mirror
        int d = p * 32 + (tid >> 3), c = (tid & 7) * 8;
        uint4 o;
        o.x = pack2(T[c][d], T[c+1][d]);   o.y = pack2(T[c+2][d], T[c+3][d]);
        o.z = pack2(T[c+4][d], T[c+5][d]); o.w = pack2(T[c+6][d], T[c+7][d]);
        *(uint4*)(kt + ((size_t)(b * DD + dt * 64 + d)) * LL + st * 64 + c) = o;
    }
}

#define CH32 12   // js32 steps per chunk -> 102 chunks/batch, grid 408

__device__ __forceinline__ void stage_krow_(const ushort_t* Kb, int j,
                                            ushort_t* dst, int w, int lane) {
#pragma unroll
    for (int cl = 0; cl < 4; ++cl) {
        int row = w * 8 + cl * 2 + (lane >> 5);
        int u = lane & 31;
        gll16(Kb + (size_t)(j * 32 + row) * DD + ((u ^ (row & 7)) * 8),
              dst + (w * 8 + cl * 2) * DD);
    }
}
__device__ __forceinline__ void stage_kt_(const ushort_t* KTb, int j,
                                          ushort_t* dst, int w, int lane) {
#pragma unroll
    for (int cl = 0; cl < 4; ++cl) {
        int d = w * 64 + cl * 16 + (lane >> 2);
        int u = lane & 3;
        gll16(KTb + (size_t)d * LL + j * 32 + ((u ^ (d & 3)) * 8),
              dst + (w * 64 + cl * 16) * 32);
    }
}

// fused: A=Q.K^T (masked) -> O = A.K, and G=K.K^T -> rowterm, pipelined.
__global__ __launch_bounds__(256, 2) void k_fused2(const float* __restrict__ qin,
                                                   const float* __restrict__ kin,
                                                   const ushort_t* __restrict__ Kbf,
                                                   const ushort_t* __restrict__ KTbf,
                                                   float* __restrict__ qout,
                                                   float* __restrict__ rowterm) {
    // [0,16K) sKrow0/1 (2x8KB); [16K,32K) sKT0/1 (2x8KB); [32K,34K) sAt. (ushort idx)
    __shared__ __align__(16) ushort_t lds[34816];   // 68KB
    ushort_t* sKrow0 = lds;
    ushort_t* sKrow1 = lds + 8192;
    ushort_t* sKT0   = lds + 16384;
    ushort_t* sKT1   = lds + 24576;
    ushort_t* sAt    = lds + 32768;
    ushort_t* sBig   = lds;               // prologue 32KB staging (overlaps sKrow0/1)

    // XCD-chunked swizzle (grid 408, %8==0): hw id -> logical chunk id
    int bid0 = blockIdx.x;
    int cpx = gridDim.x >> 3;
    int bid = (bid0 & 7) * cpx + (bid0 >> 3);

    int b = bid / 102;
    int e = bid % 102;
    int it = 0, acc = 0;
    while (true) { int n = (it / 6) + 1; if (acc + n > e) break; acc += n; ++it; }
    int c = e - acc;
    int j0 = c * CH32;
    int lim = 2 * (it + 1);
    int j1 = (j0 + CH32 < lim) ? j0 + CH32 : lim;

    const float* qb32 = qin + (size_t)b * LL * DD;
    const float* kb32 = kin + (size_t)b * LL * DD;
    const ushort_t* Kb  = Kbf  + (size_t)b * LL * DD;
    const ushort_t* KTb = KTbf + (size_t)b * DD * LL;
    int tid = threadIdx.x, lane = tid & 63, w = tid >> 6;
    int wr = w >> 1, wc = w & 1, ln = lane & 15, g = lane >> 4;

    // ---- prologue: stage Q_it then K_it from f32, extract frags
    bhalf8 qf[2][8], ktf[2][8];
#pragma unroll
    for (int pass = 0; pass < 2; ++pass) {
        const float* gt = (pass == 0 ? qb32 : kb32) + (size_t)it * 64 * DD;
#pragma unroll
        for (int m = 0; m < 16; ++m) {
            int row = m * 4 + (tid >> 6);
            int c4 = tid & 63;
            f4 v = *(const f4*)(gt + (size_t)row * DD + c4 * 4);
            uint2 pv; pv.x = pack2(v[0], v[1]); pv.y = pack2(v[2], v[3]);
            int gr = (c4 >> 1) ^ (row & 7);
            *(uint2*)&sBig[row * DD + gr * 8 + (c4 & 1) * 4] = pv;
        }
        __syncthreads();
#pragma unroll
        for (int rt = 0; rt < 2; ++rt)
#pragma unroll
            for (int kc = 0; kc < 8; ++kc) {
                int row = 32 * wr + 16 * rt + ln;
                bhalf8 v = *(const bhalf8*)&sBig[row * DD + (((kc * 4 + g) ^ (row & 7)) * 8)];
                if (pass == 0) qf[rt][kc] = v; else ktf[rt][kc] = v;
            }
        __syncthreads();
    }

    // ---- issue first tile loads (j0 -> buf0)
    stage_krow_(Kb, j0, sKrow0, w, lane);
    stage_kt_(KTb, j0, sKT0, w, lane);

    f32x4 oacc[2][8];
#pragma unroll
    for (int rt = 0; rt < 2; ++rt)
#pragma unroll
        for (int dt = 0; dt < 8; ++dt) oacc[rt][dt] = (f32x4){0.f, 0.f, 0.f, 0.f};
    float racc[2][4];
#pragma unroll
    for (int rt = 0; rt < 2; ++rt)
#pragma unroll
        for (int r = 0; r < 4; ++r) racc[rt][r] = 0.f;

    int buf = 0;
    for (int j = j0; j < j1; ++j) {
        // head: wait OWN tile-j loads (the only outstanding vmem), then barrier
        asm volatile("s_waitcnt vmcnt(0) lgkmcnt(0)\ns_barrier" ::: "memory");
        ushort_t* skr  = buf ? sKrow1 : sKrow0;
        ushort_t* skt  = buf ? sKT1 : sKT0;
        ushort_t* skrN = buf ? sKrow0 : sKrow1;
        ushort_t* sktN = buf ? sKT0 : sKT1;
        // prefetch j+1 into the other buffers (full-step slack)
        if (j + 1 < j1) {
            stage_krow_(Kb, j + 1, skrN, w, lane);
            stage_kt_(KTb, j + 1, sktN, w, lane);
        }
        // ---- A_q and G share B-fragments (rows of K_js)
        f32x4 qa[2], ga[2];
#pragma unroll
        for (int rt = 0; rt < 2; ++rt) { qa[rt] = (f32x4){0.f,0.f,0.f,0.f}; ga[rt] = (f32x4){0.f,0.f,0.f,0.f}; }
        __builtin_amdgcn_s_setprio(1);
#pragma unroll
        for (int kc = 0; kc < 8; ++kc) {
            int srow = 16 * wc + ln;
            bhalf8 bfv = *(const bhalf8*)&skr[srow * DD + (((kc * 4 + g) ^ (srow & 7)) * 8)];
#pragma unroll
            for (int rt = 0; rt < 2; ++rt) {
                qa[rt] = mfma16(qf[rt][kc], bfv, qa[rt]);
                ga[rt] = mfma16(ktf[rt][kc], bfv, ga[rt]);
            }
        }
        __builtin_amdgcn_s_setprio(0);
        // ---- mask A -> sAt (swizzled); accumulate G into racc
        int sg0 = j * 32 + 16 * wc + ln;
        int sloc_u = (2 * wc + (ln >> 3));
#pragma unroll
        for (int rt = 0; rt < 2; ++rt)
#pragma unroll
            for (int r = 0; r < 4; ++r) {
                int tloc = 32 * wr + 16 * rt + g * 4 + r;
                int tg = it * 64 + tloc;
                float av = (sg0 <= tg) ? qa[rt][r] : 0.f;
                sAt[tloc * 32 + ((sloc_u ^ (tloc & 3)) * 8) + (ln & 7)] = bf16of(av);
                float gv = ga[rt][r];
                float wgt = (sg0 < tg) ? 2.f : ((sg0 == tg) ? 1.f : 0.f);
                racc[rt][r] = fmaf(wgt * gv, gv, racc[rt][r]);
            }
        // mid: drain LDS writes only — do NOT drain the in-flight prefetch
        asm volatile("s_waitcnt lgkmcnt(0)\ns_barrier" ::: "memory");
        // ---- O += A . K_js
        bhalf8 af[2];
#pragma unroll
        for (int rt = 0; rt < 2; ++rt) {
            int tr = 32 * wr + 16 * rt + ln;
            af[rt] = *(const bhalf8*)&sAt[tr * 32 + ((g ^ (tr & 3)) * 8)];
        }
        __builtin_amdgcn_s_setprio(1);
#pragma unroll
        for (int dt = 0; dt < 8; ++dt) {
            int d = 128 * wc + 16 * dt + ln;
            bhalf8 bk = *(const bhalf8*)&skt[d * 32 + ((g ^ (d & 3)) * 8)];
#pragma unroll
            for (int rt = 0; rt < 2; ++rt)
                oacc[rt][dt] = mfma16(af[rt], bk, oacc[rt][dt]);
        }
        __builtin_amdgcn_s_setprio(0);
        buf ^= 1;
    }
    // ---- epilogue
#pragma unroll
    for (int rt = 0; rt < 2; ++rt)
#pragma unroll
        for (int dt = 0; dt < 8; ++dt)
#pragma unroll
            for (int r = 0; r < 4; ++r) {
                size_t row = (size_t)b * LL + it * 64 + 32 * wr + 16 * rt + g * 4 + r;
                atomicAdd(&qout[row * DD + 128 * wc + 16 * dt + ln], oacc[rt][dt][r]);
            }
#pragma unroll
    for (int rt = 0; rt < 2; ++rt)
#pragma unroll
        for (int r = 0; r < 4; ++r) {
            float v = racc[rt][r];
            v += __shfl_xor(v, 1); v += __shfl_xor(v, 2);
            v += __shfl_xor(v, 4); v += __shfl_xor(v, 8);
            if (ln == 0)
                atomicAdd(&rowterm[b * LL + it * 64 + 32 * wr + 16 * rt + g * 4 + r], v);
        }
}

// P_final partial: pout += K^T K over one L-quarter (reads KT mirror)
__global__ __launch_bounds__(256, 2) void k_pfinal2(const ushort_t* __restrict__ KTbf,
                                                    float* __restrict__ pout) {
    __shared__ __align__(16) ushort_t sT[256 * 64];
    int bid = blockIdx.x;
    int b = bid >> 5, slab = (bid >> 2) & 7, lq = bid & 3;
    const ushort_t* KTb = KTbf + (size_t)b * DD * LL;
    int tid = threadIdx.x, lane = tid & 63, w = tid >> 6;
    int ln = lane & 15, g = lane >> 4;
    f32x4 acc[2][4];
#pragma unroll
    for (int rt = 0; rt < 2; ++rt)
#pragma unroll
        for (int ct = 0; ct < 4; ++ct) acc[rt][ct] = (f32x4){0.f, 0.f, 0.f, 0.f};

    for (int ch = lq * 8; ch < lq * 8 + 8; ++ch) {
        __syncthreads();
#pragma unroll
        for (int cl = 0; cl < 8; ++cl) {
            int d = w * 64 + cl * 8 + (lane >> 3);
            int u = lane & 7;
            gll16(KTb + (size_t)d * LL + ch * 64 + ((u ^ (d & 7)) * 8),
                  sT + (w * 64 + cl * 8) * 64);
        }
        __syncthreads();
#pragma unroll
        for (int kc = 0; kc < 2; ++kc) {
            bhalf8 af[2];
#pragma unroll
            for (int rt = 0; rt < 2; ++rt) {
                int dr = slab * 32 + 16 * rt + ln;
                af[rt] = *(const bhalf8*)&sT[dr * 64 + (((kc * 4 + g) ^ (dr & 7)) * 8)];
            }
#pragma unroll
            for (int ct = 0; ct < 4; ++ct) {
                int dc = w * 64 + 16 * ct + ln;
                bhalf8 bf = *(const bhalf8*)&sT[dc * 64 + (((kc * 4 + g) ^ (dc & 7)) * 8)];
#pragma unroll
                for (int rt = 0; rt < 2; ++rt)
                    acc[rt][ct] = mfma16(af[rt], bf, acc[rt][ct]);
            }
        }
    }
#pragma unroll
    for (int rt = 0; rt < 2; ++rt)
#pragma unroll
        for (int ct = 0; ct < 4; ++ct)
#pragma unroll
            for (int r = 0; r < 4; ++r) {
                int i = slab * 32 + 16 * rt + g * 4 + r;
                int j = w * 64 + 16 * ct + ln;
                atomicAdd(&pout[(size_t)b * DD * DD + (size_t)i * DD + j], acc[rt][ct][r]);
            }
}

// ---- scan + epilogue --------------------------------------------------------
__global__ __launch_bounds__(256) void k_scan(const float* __restrict__ rowterm,
                                              float* __restrict__ inv) {
    int b = blockIdx.x, tid = threadIdx.x;
    __shared__ float sd[256];
    const float* rt = rowterm + b * LL;
    float v[8];
    float s = 0.f;
#pragma unroll
    for (int m = 0; m < 8; ++m) { v[m] = rt[tid * 8 + m]; s += v[m]; }
    sd[tid] = s;
    __syncthreads();
    for (int off = 1; off < 256; off <<= 1) {
        float add = (tid >= off) ? sd[tid - off] : 0.f;
        __syncthreads();
        sd[tid] += add;
        __syncthreads();
    }
    float run = sd[tid] - s;
#pragma unroll
    for (int m = 0; m < 8; ++m) {
        run += v[m];
        inv[b * LL + tid * 8 + m] = 1.f / (sqrtf(run) + EPS);
    }
}

__global__ __launch_bounds__(256, 4) void k_epi(float* __restrict__ qout,
                                                const float* __restrict__ inv,
                                                const float* __restrict__ gain,
                                                const float* __restrict__ oscale) {
    int idx = blockIdx.x * 256 + threadIdx.x;
    int row = idx >> 6;
    int c4 = idx & 63;
    f4 o = ((const f4*)qout)[idx];
    float iv = inv[row];
    f4 g4 = ((const f4*)gain)[c4];
    f4 s4 = ((const f4*)oscale)[c4];
    f4 r;
#pragma unroll
    for (int e = 0; e < 4; ++e) r[e] = tanhf(g4[e] * (o[e] * iv)) * s4[e];
    ((f4*)qout)[idx] = r;
}

// ============================ FALLBACK (round-2, validated) ==================
__device__ __forceinline__ void decode_chunk8(int e, int& it, int& c) {
    int i = 0, acc = 0;
    while (true) { int n = (i >> 3) + 1; if (acc + n > e) break; acc += n; ++i; }
    it = i; c = e - acc;
}
__device__ __forceinline__ void stage_row(const float* __restrict__ g,
                                          unsigned short* krow, int tid) {
#pragma unroll
    for (int m = 0; m < 16; ++m) {
        int row = m * 4 + (tid >> 6);
        int c4 = tid & 63;
        f4 v = *(const f4*)(g + (size_t)row * DD + c4 * 4);
        uint2 pv; pv.x = pack2(v[0], v[1]); pv.y = pack2(v[2], v[3]);
        *(uint2*)&krow[row * KROW_S + c4 * 4] = pv;
    }
}
__device__ __forceinline__ void stage_dual(const float* __restrict__ g,
                                           unsigned short* krow,
                                           unsigned short* kst, int tid) {
#pragma unroll
    for (int iter = 0; iter < 4; ++iter) {
        int dq = (tid & 15) + 16 * iter;
        int sq = tid >> 4;
        const float* gs = g + (size_t)(4 * sq) * DD + 4 * dq;
        f4 v0 = *(const f4*)(gs);
        f4 v1 = *(const f4*)(gs + DD);
        f4 v2 = *(const f4*)(gs + 2 * DD);
        f4 v3 = *(const f4*)(gs + 3 * DD);
        {
            uint2 p0; p0.x = pack2(v0[0], v0[1]); p0.y = pack2(v0[2], v0[3]);
            *(uint2*)&krow[(4 * sq + 0) * KROW_S + 4 * dq] = p0;
            uint2 p1; p1.x = pack2(v1[0], v1[1]); p1.y = pack2(v1[2], v1[3]);
            *(uint2*)&krow[(4 * sq + 1) * KROW_S + 4 * dq] = p1;
            uint2 p2; p2.x = pack2(v2[0], v2[1]); p2.y = pack2(v2[2], v2[3]);
            *(uint2*)&krow[(4 * sq + 2) * KROW_S + 4 * dq] = p2;
            uint2 p3; p3.x = pack2(v3[0], v3[1]); p3.y = pack2(v3[2], v3[3]);
            *(uint2*)&krow[(4 * sq + 3) * KROW_S + 4 * dq] = p3;
        }
#pragma unroll
        for (int i = 0; i < 4; ++i) {
            uint2 pv; pv.x = pack2(v0[i], v1[i]); pv.y = pack2(v2[i], v3[i]);
            *(uint2*)&kst[kst_off(4 * dq + i, 4 * sq)] = pv;
        }
    }
}
__global__ __launch_bounds__(256, 2) void k_gram(const float* __restrict__ kin,
                                                 float* __restrict__ rowterm) {
    __shared__ __align__(16) unsigned short sKrow[64 * KROW_S];
    int bid = blockIdx.x;
    int b = bid / 80;
    int it, c; decode_chunk8(bid % 80, it, c);
    int js0 = c * 8, js1 = (js0 + 8 < it + 1) ? js0 + 8 : it + 1;
    const float* kb = kin + (size_t)b * LL * DD;
    int tid = threadIdx.x, lane = tid & 63, w = tid >> 6;
    int wr = w >> 1, wc = w & 1, ln = lane & 15, g = lane >> 4;
    stage_row(kb + (size_t)it * 64 * DD, sKrow, tid);
    __syncthreads();
    bhalf8 ktf[2][8];
#pragma unroll
    for (int rt = 0; rt < 2; ++rt)
#pragma unroll
        for (int kc = 0; kc < 8; ++kc)
            ktf[rt][kc] = *(const bhalf8*)&sKrow[(32 * wr + 16 * rt + ln) * KROW_S + kc * 32 + g * 8];
    float racc[2][4];
#pragma unroll
    for (int rt = 0; rt < 2; ++rt)
#pragma unroll
        for (int r = 0; r < 4; ++r) racc[rt][r] = 0.f;
    for (int js = js0; js < js1; ++js) {
        __syncthreads();
        stage_row(kb + (size_t)js * 64 * DD, sKrow, tid);
        __syncthreads();
        f32x4 aacc[2][2];
#pragma unroll
        for (int rt = 0; rt < 2; ++rt)
#pragma unroll
            for (int st = 0; st < 2; ++st) aacc[rt][st] = (f32x4){0.f, 0.f, 0.f, 0.f};
#pragma unroll
        for (int kc = 0; kc < 8; ++kc) {
            bhalf8 bf0 = *(const bhalf8*)&sKrow[(32 * wc + ln) * KROW_S + kc * 32 + g * 8];
            bhalf8 bf1 = *(const bhalf8*)&sKrow[(32 * wc + 16 + ln) * KROW_S + kc * 32 + g * 8];
#pragma unroll
            for (int rt = 0; rt < 2; ++rt) {
                aacc[rt][0] = mfma16(ktf[rt][kc], bf0, aacc[rt][0]);
                aacc[rt][1] = mfma16(ktf[rt][kc], bf1, aacc[rt][1]);
            }
        }
#pragma unroll
        for (int rt = 0; rt < 2; ++rt)
#pragma unroll
            for (int r = 0; r < 4; ++r) {
                int tg = it * 64 + 32 * wr + 16 * rt + g * 4 + r;
                float s = 0.f;
#pragma unroll
                for (int st = 0; st < 2; ++st) {
                    int sg_ = js * 64 + 32 * wc + 16 * st + ln;
                    float dv = aacc[rt][st][r];
                    float wgt = (sg_ < tg) ? 2.f : ((sg_ == tg) ? 1.f : 0.f);
                    s += wgt * dv * dv;
                }
                racc[rt][r] += s;
            }
    }
#pragma unroll
    for (int rt = 0; rt < 2; ++rt)
#pragma unroll
        for (int r = 0; r < 4; ++r) {
            float v = racc[rt][r];
            v += __shfl_xor(v, 1); v += __shfl_xor(v, 2);
            v += __shfl_xor(v, 4); v += __shfl_xor(v, 8);
            if (ln == 0)
                atomicAdd(&rowterm[b * LL + it * 64 + 32 * wr + 16 * rt + g * 4 + r], v);
        }
}
__global__ __launch_bounds__(256, 2) void k_main(const float* __restrict__ qin,
                                                 const float* __restrict__ kin,
                                                 float* __restrict__ qout) {
    __shared__ __align__(16) unsigned short sKrow[64 * KROW_S];
    __shared__ __align__(16) unsigned short sKT[256 * KST_S];
    __shared__ __align__(16) unsigned short sAt[64 * AT_S];
    int bid = blockIdx.x;
    int b = bid / 80;
    int it, c; decode_chunk8(bid % 80, it, c);
    int js0 = c * 8, js1 = (js0 + 8 < it + 1) ? js0 + 8 : it + 1;
    const float* qb = qin + (size_t)b * LL * DD;
    const float* kb = kin + (size_t)b * LL * DD;
    int tid = threadIdx.x, lane = tid & 63, w = tid >> 6;
    int wr = w >> 1, wc = w & 1, ln = lane & 15, g = lane >> 4;
    stage_row(qb + (size_t)it * 64 * DD, sKrow, tid);
    __syncthreads();
    bhalf8 qf[2][8];
#pragma unroll
    for (int rt = 0; rt < 2; ++rt)
#pragma unroll
        for (int kc = 0; kc < 8; ++kc)
            qf[rt][kc] = *(const bhalf8*)&sKrow[(32 * wr + 16 * rt + ln) * KROW_S + kc * 32 + g * 8];
    f32x4 oacc[2][8];
#pragma unroll
    for (int rt = 0; rt < 2; ++rt)
#pragma unroll
        for (int dt = 0; dt < 8; ++dt) oacc[rt][dt] = (f32x4){0.f, 0.f, 0.f, 0.f};
    for (int js = js0; js < js1; ++js) {
        __syncthreads();
        stage_dual(kb + (size_t)js * 64 * DD, sKrow, sKT, tid);
        __syncthreads();
        f32x4 aacc[2][2];
#pragma unroll
        for (int rt = 0; rt < 2; ++rt)
#pragma unroll
            for (int st = 0; st < 2; ++st) aacc[rt][st] = (f32x4){0.f, 0.f, 0.f, 0.f};
#pragma unroll
        for (int kc = 0; kc < 8; ++kc) {
            bhalf8 bf0 = *(const bhalf8*)&sKrow[(32 * wc + ln) * KROW_S + kc * 32 + g * 8];
            bhalf8 bf1 = *(const bhalf8*)&sKrow[(32 * wc + 16 + ln) * KROW_S + kc * 32 + g * 8];
#pragma unroll
            for (int rt = 0; rt < 2; ++rt) {
                aacc[rt][0] = mfma16(qf[rt][kc], bf0, aacc[rt][0]);
                aacc[rt][1] = mfma16(qf[rt][kc], bf1, aacc[rt][1]);
            }
        }
#pragma unroll
        for (int rt = 0; rt < 2; ++rt)
#pragma unroll
            for (int st = 0; st < 2; ++st)
#pragma unroll
                for (int r = 0; r < 4; ++r) {
                    int rloc = 32 * wr + 16 * rt + g * 4 + r;
                    int sloc = 32 * wc + 16 * st + ln;
                    float v = ((js * 64 + sloc) <= (it * 64 + rloc)) ? aacc[rt][st][r] : 0.f;
                    sAt[rloc * AT_S + sloc] = bf16of(v);
                }
        __syncthreads();
#pragma unroll
        for (int kc2 = 0; kc2 < 2; ++kc2) {
            bhalf8 af[2];
#pragma unroll
            for (int rt = 0; rt < 2; ++rt)
                af[rt] = *(const bhalf8*)&sAt[(32 * wr + 16 * rt + ln) * AT_S + kc2 * 32 + g * 8];
#pragma unroll
            for (int dt = 0; dt < 8; ++dt) {
                int d = 128 * wc + 16 * dt + ln;
                bhalf8 bf = *(const bhalf8*)&sKT[kst_off(d, kc2 * 32 + g * 8)];
#pragma unroll
                for (int rt = 0; rt < 2; ++rt)
                    oacc[rt][dt] = mfma16(af[rt], bf, oacc[rt][dt]);
            }
        }
    }
#pragma unroll
    for (int rt = 0; rt < 2; ++rt)
#pragma unroll
        for (int dt = 0; dt < 8; ++dt)
#pragma unroll
            for (int r = 0; r < 4; ++r) {
                size_t row = (size_t)b * LL + it * 64 + 32 * wr + 16 * rt + g * 4 + r;
                atomicAdd(&qout[row * DD + 128 * wc + 16 * dt + ln], oacc[rt][dt][r]);
            }
}
__global__ __launch_bounds__(256, 2) void k_pfinal(const float* __restrict__ kin,
                                                   float* __restrict__ pout) {
    __shared__ __align__(16) unsigned short sKT[256 * KST_S];
    int bid = blockIdx.x;
    int b = bid >> 5;
    int slab = (bid >> 2) & 7;
    int lq = bid & 3;
    const float* kb = kin + (size_t)b * LL * DD;
    int tid = threadIdx.x, lane = tid & 63, w = tid >> 6;
    int ln = lane & 15, g = lane >> 4;
    f32x4 acc[2][4];
#pragma unroll
    for (int rt = 0; rt < 2; ++rt)
#pragma unroll
        for (int ct = 0; ct < 4; ++ct) acc[rt][ct] = (f32x4){0.f, 0.f, 0.f, 0.f};
    for (int ch = lq * 8; ch < lq * 8 + 8; ++ch) {
        __syncthreads();
#pragma unroll
        for (int iter = 0; iter < 4; ++iter) {
            int dq = (tid & 15) + 16 * iter;
            int sq = tid >> 4;
            const float* gs = kb + (size_t)(ch * 64 + 4 * sq) * DD + 4 * dq;
            f4 v0 = *(const f4*)(gs);
            f4 v1 = *(const f4*)(gs + DD);
            f4 v2 = *(const f4*)(gs + 2 * DD);
            f4 v3 = *(const f4*)(gs + 3 * DD);
#pragma unroll
            for (int i = 0; i < 4; ++i) {
                uint2 pv; pv.x = pack2(v0[i], v1[i]); pv.y = pack2(v2[i], v3[i]);
                *(uint2*)&sKT[kst_off(4 * dq + i, 4 * sq)] = pv;
            }
        }
        __syncthreads();
#pragma unroll
        for (int kc = 0; kc < 2; ++kc) {
            bhalf8 af[2];
#pragma unroll
            for (int rt = 0; rt < 2; ++rt)
                af[rt] = *(const bhalf8*)&sKT[kst_off(slab * 32 + 16 * rt + ln, kc * 32 + g * 8)];
#pragma unroll
            for (int ct = 0; ct < 4; ++ct) {
                bhalf8 bf = *(const bhalf8*)&sKT[kst_off(64 * w + 16 * ct + ln, kc * 32 + g * 8)];
#pragma unroll
                for (int rt = 0; rt < 2; ++rt)
                    acc[rt][ct] = mfma16(af[rt], bf, acc[rt][ct]);
            }
        }
    }
#pragma unroll
    for (int rt = 0; rt < 2; ++rt)
#pragma unroll
        for (int ct = 0; ct < 4; ++ct)
#pragma unroll
            for (int r = 0; r < 4; ++r) {
                int i = slab * 32 + 16 * rt + g * 4 + r;
                int j = 64 * w + 16 * ct + ln;
                atomicAdd(&pout[(size_t)b * DD * DD + (size_t)i * DD + j], acc[rt][ct][r]);
            }
}

// ============================ launch =========================================
extern "C" void kernel_launch(void* const* d_in, const int* in_sizes, int n_in,
                              void* d_out, int out_size, void* d_ws, size_t ws_size,
                              hipStream_t stream) {
    const float* q      = (const float*)d_in[0];
    const float* k      = (const float*)d_in[1];
    const float* pprev  = (const float*)d_in[2];
    const float* gain   = (const float*)d_in[3];
    const float* oscale = (const float*)d_in[4];
    float* qout = (float*)d_out;
    float* pout = qout + (size_t)NB * LL * DD;

    size_t mirror_elems = (size_t)NB * LL * DD;
    size_t need = mirror_elems * 2 * 2 + (size_t)2 * NB * LL * 4;   // 8MB + 64KB

    if (ws_size >= need) {
        ushort_t* Kbf  = (ushort_t*)d_ws;
        ushort_t* KTbf = Kbf + mirror_elems;
        float* rowterm = (float*)(KTbf + mirror_elems);
        float* invp    = rowterm + NB * LL;

        hipMemsetAsync(qout, 0, (size_t)NB * LL * DD * 4, stream);
        k_convK  <<<512, 256, 0, stream>>>(k, Kbf, KTbf, rowterm);
        k_fused2 <<<NB * 102, 256, 0, stream>>>(q, k, Kbf, KTbf, qout, rowterm);
        k_scan   <<<NB, 256, 0, stream>>>(rowterm, invp);
        k_epi    <<<NB * LL * DD / 1024, 256, 0, stream>>>(qout, invp, gain, oscale);
        hipMemcpyAsync(pout, pprev, (size_t)NB * DD * DD * 4, hipMemcpyDeviceToDevice, stream);
        k_pfinal2<<<128, 256, 0, stream>>>(KTbf, pout);
    } else {
        float* rowterm = pout;
        float* invp    = pout + NB * LL;
        hipMemsetAsync(qout, 0, (size_t)NB * LL * DD * 4, stream);
        hipMemsetAsync(pout, 0, (size_t)2 * NB * LL * 4, stream);
        k_gram  <<<NB * 80, 256, 0, stream>>>(k, rowterm);
        k_scan  <<<NB, 256, 0, stream>>>(rowterm, invp);
        k_main  <<<NB * 80, 256, 0, stream>>>(q, k, qout);
        k_epi   <<<NB * LL * DD / 1024, 256, 0, stream>>>(qout, invp, gain, oscale);
        hipMemcpyAsync(pout, pprev, (size_t)NB * DD * DD * 4, hipMemcpyDeviceToDevice, stream);
        k_pfinal<<<128, 256, 0, stream>>>(k, pout);
    }
}